// Round 4
// baseline (155.187 us; speedup 1.0000x reference)
//
#include <hip/hip_runtime.h>

// QuantumTextClassifier: embed+PE -> 4x {q=cumprod(cos(x)); x=LN(x+q); x=LN(x+q)}
// -> mean over T -> @W + b.
// Mapping: 2 rows per wave (32 lanes/row, float4 per lane).
// cumprod = 5-step DPP multiplicative scan per 32-half;
// LN sums = 4x DPP butterfly + ds_swizzle(xor16), result in ALL lanes (no readlane).

#define NBLK 4
#define E_DIM 128
#define T_LEN 2048
#define B_SZ 32
#define C_CLS 4
#define LN_EPS 1e-5f
#define WG_PER_B 64                         // workgroups per batch element
#define WAVES_PER_WG 4
#define WAVES_PER_B (WG_PER_B * WAVES_PER_WG)  // 256
#define N_ITER 4                            // 2048 tokens / (256 waves * 2 rows)
#define T_STEP 512                          // token stride per iteration

#define F_ONE 0x3F800000                    // bit pattern of 1.0f

// DPP move with old-value semantics (multiplicative scan: invalid/masked -> OLD).
template <int CTRL, int RMASK, int OLDBITS>
__device__ __forceinline__ float dppf(float v) {
    return __int_as_float(__builtin_amdgcn_update_dpp(
        OLDBITS, __float_as_int(v), CTRL, RMASK, 0xF, false));
}

// Fused-add DPP step (bound_ctrl=1: invalid lanes contribute 0).
template <int CTRL, int RMASK>
__device__ __forceinline__ float dpp_add(float s) {
    return s + __int_as_float(__builtin_amdgcn_update_dpp(
        0, __float_as_int(s), CTRL, RMASK, 0xF, true));
}

// Sum over each 32-lane half; result broadcast to every lane of the half.
__device__ __forceinline__ float half_sum(float s) {
    s = dpp_add<0xB1,  0xF>(s);   // quad_perm [1,0,3,2]  ~ xor1
    s = dpp_add<0x4E,  0xF>(s);   // quad_perm [2,3,0,1]  ~ xor2
    s = dpp_add<0x141, 0xF>(s);   // row_half_mirror      ~ xor4 (quads equal)
    s = dpp_add<0x140, 0xF>(s);   // row_mirror           ~ xor8
    // xor16 within each 32-lane group -> LDS pipe, no bank conflicts
    s += __int_as_float(__builtin_amdgcn_ds_swizzle(__float_as_int(s), 0x401F));
    return s;
}

__device__ __forceinline__ void ln4(float y0, float y1, float y2, float y3,
                                    const float4 g, const float4 be,
                                    float& o0, float& o1, float& o2, float& o3) {
    const float s  = half_sum((y0 + y1) + (y2 + y3));
    const float s2 = half_sum(fmaf(y0, y0, fmaf(y1, y1, fmaf(y2, y2, y3 * y3))));
    const float mu  = s * (1.0f / 128.0f);
    const float var = fmaf(s2, 1.0f / 128.0f, -mu * mu);
    const float r   = rsqrtf(var + LN_EPS);
    o0 = fmaf((y0 - mu) * r, g.x, be.x);
    o1 = fmaf((y1 - mu) * r, g.y, be.y);
    o2 = fmaf((y2 - mu) * r, g.z, be.z);
    o3 = fmaf((y3 - mu) * r, g.w, be.w);
}

__global__ __launch_bounds__(256, 4) void qtc_main(
    const int*   __restrict__ tokens,   // [B, T]
    const float* __restrict__ emb,      // [V, E]
    const float* __restrict__ g1,       // [NBLK, E]
    const float* __restrict__ b1,
    const float* __restrict__ g2,
    const float* __restrict__ b2,
    float*       __restrict__ pooled)   // [B, E] accumulator (pre-zeroed)
{
    const int lane = threadIdx.x & 63;
    const int wave = threadIdx.x >> 6;
    const int b    = blockIdx.x / WG_PER_B;
    const int wgb  = blockIdx.x % WG_PER_B;
    const int el   = lane & 31;         // element-group within row
    const int e0   = el * 4;            // first of 4 contiguous elems
    const int half = lane >> 5;         // which row of the wave's pair
    const int wid  = wgb * WAVES_PER_WG + wave;     // [0, 256) within batch
    const bool row_head = ((lane & 15) == 0);       // lanes 0,16,32,48

    // LN params: 16 float4 = 64 VGPRs
    float4 G1[NBLK], B1[NBLK], G2[NBLK], B2[NBLK];
    #pragma unroll
    for (int i = 0; i < NBLK; ++i) {
        G1[i] = *reinterpret_cast<const float4*>(&g1[i * E_DIM + e0]);
        B1[i] = *reinterpret_cast<const float4*>(&b1[i * E_DIM + e0]);
        G2[i] = *reinterpret_cast<const float4*>(&g2[i * E_DIM + e0]);
        B2[i] = *reinterpret_cast<const float4*>(&b2[i * E_DIM + e0]);
    }

    // PE freqs for elem pairs (e0,e0+1) and (e0+2,e0+3)
    const float dfac0 = expf(-(float)e0       * (9.210340371976184f / 128.0f));
    const float dfac1 = expf(-(float)(e0 + 2) * (9.210340371976184f / 128.0f));
    const float tst   = (float)(wid + 256 * half);
    float pes0 = sinf(tst * dfac0), pec0 = cosf(tst * dfac0);
    float pes1 = sinf(tst * dfac1), pec1 = cosf(tst * dfac1);
    const float dS0 = sinf((float)T_STEP * dfac0), dC0 = cosf((float)T_STEP * dfac0);
    const float dS1 = sinf((float)T_STEP * dfac1), dC1 = cosf((float)T_STEP * dfac1);

    float sum0 = 0.0f, sum1 = 0.0f, sum2 = 0.0f, sum3 = 0.0f;
    int tix = b * T_LEN + wid + 256 * half;

    #pragma unroll
    for (int k = 0; k < N_ITER; ++k) {
        const int tok = tokens[tix];
        tix += T_STEP;
        const float4 xv = *reinterpret_cast<const float4*>(&emb[tok * E_DIM + e0]);
        float x0 = xv.x + pes0, x1 = xv.y + pec0;
        float x2 = xv.z + pes1, x3 = xv.w + pec1;
        // rotate PE to next token (angle addition)
        {
            float ns = fmaf(pes0, dC0, pec0 * dS0);
            pec0     = fmaf(pec0, dC0, -pes0 * dS0);
            pes0     = ns;
            ns       = fmaf(pes1, dC1, pec1 * dS1);
            pec1     = fmaf(pec1, dC1, -pes1 * dS1);
            pes1     = ns;
        }

        #pragma unroll
        for (int i = 0; i < NBLK; ++i) {
            // cumprod(cos(x)) along the 128-elem row (32 lanes x 4)
            const float t0 = __cosf(x0), t1 = __cosf(x1);
            const float t2 = __cosf(x2), t3 = __cosf(x3);
            const float lp1 = t0 * t1, lp2 = lp1 * t2, lp3 = lp2 * t3;
            float sc = lp3;
            sc *= dppf<0x111, 0xF, F_ONE>(sc);   // row_shr:1
            sc *= dppf<0x112, 0xF, F_ONE>(sc);   // row_shr:2
            sc *= dppf<0x114, 0xF, F_ONE>(sc);   // row_shr:4
            sc *= dppf<0x118, 0xF, F_ONE>(sc);   // row_shr:8
            const float t15 = dppf<0x142, 0xA, F_ONE>(sc);  // bcast15 -> rows 1,3
            sc *= t15;                            // inclusive over 32-half
            // exclusive = shr1 of inclusive; patch heads:
            // lane0/32 -> 1 (t15 kept old=1 there), lane16/48 -> t15
            float ex = dppf<0x111, 0xF, F_ONE>(sc);
            ex = row_head ? t15 : ex;
            const float q0 = ex * t0,  q1 = ex * lp1;
            const float q2 = ex * lp2, q3 = ex * lp3;

            // x = LN(x + q) twice (same q)
            ln4(x0 + q0, x1 + q1, x2 + q2, x3 + q3, G1[i], B1[i], x0, x1, x2, x3);
            ln4(x0 + q0, x1 + q1, x2 + q2, x3 + q3, G2[i], B2[i], x0, x1, x2, x3);
        }
        sum0 += x0; sum1 += x1; sum2 += x2; sum3 += x3;
    }

    // both halves target the same pooled[b] row; atomics merge them
    atomicAdd(&pooled[b * E_DIM + e0 + 0], sum0);
    atomicAdd(&pooled[b * E_DIM + e0 + 1], sum1);
    atomicAdd(&pooled[b * E_DIM + e0 + 2], sum2);
    atomicAdd(&pooled[b * E_DIM + e0 + 3], sum3);
}

__global__ __launch_bounds__(64) void qtc_final(
    const float* __restrict__ pooled,  // [B, E] sums over T
    const float* __restrict__ W,       // [E, C]
    const float* __restrict__ bias,    // [C]
    float*       __restrict__ out)     // [B, C]
{
    const int b    = blockIdx.x;       // one wave per batch element
    const int lane = threadIdx.x;
    const int e0   = 2 * lane;
    const float p0 = pooled[b * E_DIM + e0];
    const float p1 = pooled[b * E_DIM + e0 + 1];
    float acc[C_CLS];
    #pragma unroll
    for (int c = 0; c < C_CLS; ++c)
        acc[c] = fmaf(p0, W[e0 * C_CLS + c], p1 * W[(e0 + 1) * C_CLS + c]);
    #pragma unroll
    for (int c = 0; c < C_CLS; ++c) {
        float s = acc[c];
        s = dpp_add<0x111, 0xF>(s);   // row_shr:1
        s = dpp_add<0x112, 0xF>(s);   // row_shr:2
        s = dpp_add<0x114, 0xF>(s);   // row_shr:4
        s = dpp_add<0x118, 0xF>(s);   // row_shr:8
        s = dpp_add<0x142, 0xA>(s);   // row_bcast15 -> rows 1,3
        s = dpp_add<0x143, 0xC>(s);   // row_bcast31 -> rows 2,3
        acc[c] = s;                    // total lives in lane 63
    }
    if (lane == 63) {
        #pragma unroll
        for (int c = 0; c < C_CLS; ++c)
            out[b * C_CLS + c] = fmaf(acc[c], 1.0f / (float)T_LEN, bias[c]);
    }
}

extern "C" void kernel_launch(void* const* d_in, const int* in_sizes, int n_in,
                              void* d_out, int out_size, void* d_ws, size_t ws_size,
                              hipStream_t stream) {
    const int*   tokens = (const int*)  d_in[0];
    const float* emb    = (const float*)d_in[1];
    const float* g1     = (const float*)d_in[2];
    const float* b1     = (const float*)d_in[3];
    const float* g2     = (const float*)d_in[4];
    const float* b2     = (const float*)d_in[5];
    // d_in[6] = q_weights: provably unused by the reference
    const float* W      = (const float*)d_in[7];
    const float* bias   = (const float*)d_in[8];
    float* out    = (float*)d_out;
    float* pooled = (float*)d_ws;      // B*E floats = 16 KB

    hipMemsetAsync(pooled, 0, B_SZ * E_DIM * sizeof(float), stream);
    qtc_main<<<B_SZ * WG_PER_B, 256, 0, stream>>>(tokens, emb, g1, b1, g2, b2, pooled);
    qtc_final<<<B_SZ, 64, 0, stream>>>(pooled, W, bias, out);
}

// Round 5
// 39.141 us; speedup vs baseline: 3.9648x; 3.9648x over previous
//
#include <hip/hip_runtime.h>

// QuantumTextClassifier: embed+PE -> 4x {q=cumprod(cos(x)); x=LN(x+q); x=LN(x+q)}
// -> mean over T -> @W + b.
// Mapping: 2 rows per wave (32 lanes/row, float4 per lane).
// cumprod = 5-step DPP multiplicative scan per 32-half;
// LN sums = 4x fused DPP butterfly + ds_swizzle(xor16), result in ALL lanes.
// Pooling: LDS per-block reduction -> 1 atomicAdd per element per block
// (kills the intra-wave same-address atomic serialization of the prior rev).

#define NBLK 4
#define E_DIM 128
#define T_LEN 2048
#define B_SZ 32
#define C_CLS 4
#define LN_EPS 1e-5f
#define WG_PER_B 64                         // workgroups per batch element
#define WAVES_PER_WG 4
#define N_ITER 4                            // 2048 / (64 wg * 4 waves * 2 rows)
#define T_STEP 512                          // token stride per iteration

#define F_ONE 0x3F800000                    // bit pattern of 1.0f

// DPP move with old-value semantics (multiplicative scan: invalid/masked -> OLD).
template <int CTRL, int RMASK, int OLDBITS>
__device__ __forceinline__ float dppf(float v) {
    return __int_as_float(__builtin_amdgcn_update_dpp(
        OLDBITS, __float_as_int(v), CTRL, RMASK, 0xF, false));
}

// Fused-add DPP step (bound_ctrl=1: invalid lanes contribute 0).
template <int CTRL, int RMASK>
__device__ __forceinline__ float dpp_add(float s) {
    return s + __int_as_float(__builtin_amdgcn_update_dpp(
        0, __float_as_int(s), CTRL, RMASK, 0xF, true));
}

// Sum over each 32-lane half; result broadcast to every lane of the half.
__device__ __forceinline__ float half_sum(float s) {
    s = dpp_add<0xB1,  0xF>(s);   // quad_perm [1,0,3,2]  ~ xor1
    s = dpp_add<0x4E,  0xF>(s);   // quad_perm [2,3,0,1]  ~ xor2
    s = dpp_add<0x141, 0xF>(s);   // row_half_mirror      ~ xor4
    s = dpp_add<0x140, 0xF>(s);   // row_mirror           ~ xor8
    // xor16 within each 32-lane group (LDS pipe, conflict-free)
    s += __int_as_float(__builtin_amdgcn_ds_swizzle(__float_as_int(s), 0x401F));
    return s;
}

__device__ __forceinline__ void ln4(float y0, float y1, float y2, float y3,
                                    const float4 g, const float4 be,
                                    float& o0, float& o1, float& o2, float& o3) {
    const float s  = half_sum((y0 + y1) + (y2 + y3));
    const float s2 = half_sum(fmaf(y0, y0, fmaf(y1, y1, fmaf(y2, y2, y3 * y3))));
    const float mu  = s * (1.0f / 128.0f);
    const float var = fmaf(s2, 1.0f / 128.0f, -mu * mu);
    const float r   = rsqrtf(var + LN_EPS);
    o0 = fmaf((y0 - mu) * r, g.x, be.x);
    o1 = fmaf((y1 - mu) * r, g.y, be.y);
    o2 = fmaf((y2 - mu) * r, g.z, be.z);
    o3 = fmaf((y3 - mu) * r, g.w, be.w);
}

__global__ __launch_bounds__(256, 4) void qtc_main(
    const int*   __restrict__ tokens,   // [B, T]
    const float* __restrict__ emb,      // [V, E]
    const float* __restrict__ g1,       // [NBLK, E]
    const float* __restrict__ b1,
    const float* __restrict__ g2,
    const float* __restrict__ b2,
    float*       __restrict__ pooled)   // [B, E] accumulator (pre-zeroed)
{
    __shared__ float part[WAVES_PER_WG][2][E_DIM];   // 4 KB

    const int lane = threadIdx.x & 63;
    const int wave = threadIdx.x >> 6;
    const int b    = blockIdx.x / WG_PER_B;
    const int wgb  = blockIdx.x % WG_PER_B;
    const int el   = lane & 31;         // element-group within row
    const int e0   = el * 4;            // first of 4 contiguous elems
    const int half = lane >> 5;         // which row of the wave's pair
    const int wid  = wgb * WAVES_PER_WG + wave;     // [0, 256) within batch
    const bool row_head = ((lane & 15) == 0);       // lanes 0,16,32,48

    // LN params: 16 float4 = 64 VGPRs
    float4 G1[NBLK], B1[NBLK], G2[NBLK], B2[NBLK];
    #pragma unroll
    for (int i = 0; i < NBLK; ++i) {
        G1[i] = *reinterpret_cast<const float4*>(&g1[i * E_DIM + e0]);
        B1[i] = *reinterpret_cast<const float4*>(&b1[i * E_DIM + e0]);
        G2[i] = *reinterpret_cast<const float4*>(&g2[i * E_DIM + e0]);
        B2[i] = *reinterpret_cast<const float4*>(&b2[i * E_DIM + e0]);
    }

    // PE freqs for elem pairs (e0,e0+1) and (e0+2,e0+3); native trig only.
    const float dfac0 = __expf(-(float)e0       * (9.210340371976184f / 128.0f));
    const float dfac1 = __expf(-(float)(e0 + 2) * (9.210340371976184f / 128.0f));
    const float tst   = (float)(wid + 256 * half);
    float pes0 = __sinf(tst * dfac0), pec0 = __cosf(tst * dfac0);
    float pes1 = __sinf(tst * dfac1), pec1 = __cosf(tst * dfac1);
    const float dS0 = __sinf((float)T_STEP * dfac0), dC0 = __cosf((float)T_STEP * dfac0);
    const float dS1 = __sinf((float)T_STEP * dfac1), dC1 = __cosf((float)T_STEP * dfac1);

    float sum0 = 0.0f, sum1 = 0.0f, sum2 = 0.0f, sum3 = 0.0f;
    int tix = b * T_LEN + wid + 256 * half;

    #pragma unroll
    for (int k = 0; k < N_ITER; ++k) {
        const int tok = tokens[tix];
        tix += T_STEP;
        const float4 xv = *reinterpret_cast<const float4*>(&emb[tok * E_DIM + e0]);
        float x0 = xv.x + pes0, x1 = xv.y + pec0;
        float x2 = xv.z + pes1, x3 = xv.w + pec1;
        // rotate PE to next token (angle addition)
        {
            float ns = fmaf(pes0, dC0, pec0 * dS0);
            pec0     = fmaf(pec0, dC0, -pes0 * dS0);
            pes0     = ns;
            ns       = fmaf(pes1, dC1, pec1 * dS1);
            pec1     = fmaf(pec1, dC1, -pes1 * dS1);
            pes1     = ns;
        }

        #pragma unroll
        for (int i = 0; i < NBLK; ++i) {
            // cumprod(cos(x)) along the 128-elem row (32 lanes x 4)
            const float t0 = __cosf(x0), t1 = __cosf(x1);
            const float t2 = __cosf(x2), t3 = __cosf(x3);
            const float lp1 = t0 * t1, lp2 = lp1 * t2, lp3 = lp2 * t3;
            float sc = lp3;
            sc *= dppf<0x111, 0xF, F_ONE>(sc);   // row_shr:1
            sc *= dppf<0x112, 0xF, F_ONE>(sc);   // row_shr:2
            sc *= dppf<0x114, 0xF, F_ONE>(sc);   // row_shr:4
            sc *= dppf<0x118, 0xF, F_ONE>(sc);   // row_shr:8
            const float t15 = dppf<0x142, 0xA, F_ONE>(sc);  // bcast15 -> rows 1,3
            sc *= t15;                            // inclusive over 32-half
            // exclusive = shr1 of inclusive; heads: lane0/32 -> 1 (t15 old),
            // lane16/48 -> t15
            float ex = dppf<0x111, 0xF, F_ONE>(sc);
            ex = row_head ? t15 : ex;
            const float q0 = ex * t0,  q1 = ex * lp1;
            const float q2 = ex * lp2, q3 = ex * lp3;

            // x = LN(x + q) twice (same q)
            ln4(x0 + q0, x1 + q1, x2 + q2, x3 + q3, G1[i], B1[i], x0, x1, x2, x3);
            ln4(x0 + q0, x1 + q1, x2 + q2, x3 + q3, G2[i], B2[i], x0, x1, x2, x3);
        }
        sum0 += x0; sum1 += x1; sum2 += x2; sum3 += x3;
    }

    // block-level pooling: disjoint LDS writes, then 1 atomic per elem per block
    float4* dst = reinterpret_cast<float4*>(&part[wave][half][e0]);
    *dst = make_float4(sum0, sum1, sum2, sum3);
    __syncthreads();
    if (threadIdx.x < E_DIM) {
        const int e = threadIdx.x;
        float s = 0.0f;
        #pragma unroll
        for (int w = 0; w < WAVES_PER_WG; ++w)
            s += part[w][0][e] + part[w][1][e];
        atomicAdd(&pooled[b * E_DIM + e], s);
    }
}

__global__ __launch_bounds__(64) void qtc_final(
    const float* __restrict__ pooled,  // [B, E] sums over T
    const float* __restrict__ W,       // [E, C]
    const float* __restrict__ bias,    // [C]
    float*       __restrict__ out)     // [B, C]
{
    const int b    = blockIdx.x;       // one wave per batch element
    const int lane = threadIdx.x;
    const int e0   = 2 * lane;
    const float p0 = pooled[b * E_DIM + e0];
    const float p1 = pooled[b * E_DIM + e0 + 1];
    float acc[C_CLS];
    #pragma unroll
    for (int c = 0; c < C_CLS; ++c)
        acc[c] = fmaf(p0, W[e0 * C_CLS + c], p1 * W[(e0 + 1) * C_CLS + c]);
    #pragma unroll
    for (int c = 0; c < C_CLS; ++c) {
        float s = acc[c];
        s = dpp_add<0x111, 0xF>(s);   // row_shr:1
        s = dpp_add<0x112, 0xF>(s);   // row_shr:2
        s = dpp_add<0x114, 0xF>(s);   // row_shr:4
        s = dpp_add<0x118, 0xF>(s);   // row_shr:8
        s = dpp_add<0x142, 0xA>(s);   // row_bcast15 -> rows 1,3
        s = dpp_add<0x143, 0xC>(s);   // row_bcast31 -> rows 2,3
        acc[c] = s;                    // total lives in lane 63
    }
    if (lane == 63) {
        #pragma unroll
        for (int c = 0; c < C_CLS; ++c)
            out[b * C_CLS + c] = fmaf(acc[c], 1.0f / (float)T_LEN, bias[c]);
    }
}

extern "C" void kernel_launch(void* const* d_in, const int* in_sizes, int n_in,
                              void* d_out, int out_size, void* d_ws, size_t ws_size,
                              hipStream_t stream) {
    const int*   tokens = (const int*)  d_in[0];
    const float* emb    = (const float*)d_in[1];
    const float* g1     = (const float*)d_in[2];
    const float* b1     = (const float*)d_in[3];
    const float* g2     = (const float*)d_in[4];
    const float* b2     = (const float*)d_in[5];
    // d_in[6] = q_weights: provably unused by the reference
    const float* W      = (const float*)d_in[7];
    const float* bias   = (const float*)d_in[8];
    float* out    = (float*)d_out;
    float* pooled = (float*)d_ws;      // B*E floats = 16 KB

    hipMemsetAsync(pooled, 0, B_SZ * E_DIM * sizeof(float), stream);
    qtc_main<<<B_SZ * WG_PER_B, 256, 0, stream>>>(tokens, emb, g1, b1, g2, b2, pooled);
    qtc_final<<<B_SZ, 64, 0, stream>>>(pooled, W, bias, out);
}

// Round 6
// 37.659 us; speedup vs baseline: 4.1209x; 1.0394x over previous
//
#include <hip/hip_runtime.h>

// QuantumTextClassifier: embed+PE -> 4x {q=cumprod(cos(x)); x=LN(x+q); x=LN(x+q)}
// -> mean over T -> @W + b.
// Mapping: 2 rows per wave (32 lanes/row, float4 per lane); each wave processes
// TWO token-chains (t, t+512) manually interleaved for ILP (the serial
// scan->LN->LN chain is latency-bound; two independent chains fill the pipe).
// Pooling: per-block LDS reduce -> disjoint partial row in d_ws (no atomics,
// no memset); qtc_final reduces 64 partials per batch + tiny matmul.

#define NBLK 4
#define E_DIM 128
#define T_LEN 2048
#define B_SZ 32
#define C_CLS 4
#define LN_EPS 1e-5f
#define WG_PER_B 64                         // workgroups per batch element
#define WAVES_PER_WG 4
#define NUM_WG (B_SZ * WG_PER_B)            // 2048

#define F_ONE 0x3F800000                    // bit pattern of 1.0f

// DPP move with old-value semantics (multiplicative scan: invalid/masked -> OLD).
template <int CTRL, int RMASK, int OLDBITS>
__device__ __forceinline__ float dppf(float v) {
    return __int_as_float(__builtin_amdgcn_update_dpp(
        OLDBITS, __float_as_int(v), CTRL, RMASK, 0xF, false));
}

// Fused-add DPP step (bound_ctrl=1: invalid lanes contribute 0).
template <int CTRL, int RMASK>
__device__ __forceinline__ float dpp_add(float s) {
    return s + __int_as_float(__builtin_amdgcn_update_dpp(
        0, __float_as_int(s), CTRL, RMASK, 0xF, true));
}

// Sum over each 32-lane half; result broadcast to every lane of the half.
__device__ __forceinline__ float half_sum(float s) {
    s = dpp_add<0xB1,  0xF>(s);   // quad_perm [1,0,3,2]  ~ xor1
    s = dpp_add<0x4E,  0xF>(s);   // quad_perm [2,3,0,1]  ~ xor2
    s = dpp_add<0x141, 0xF>(s);   // row_half_mirror      ~ xor4
    s = dpp_add<0x140, 0xF>(s);   // row_mirror           ~ xor8
    // xor16 within each 32-lane group (LDS pipe, conflict-free)
    s += __int_as_float(__builtin_amdgcn_ds_swizzle(__float_as_int(s), 0x401F));
    return s;
}

// cumprod(cos(x)) over the 128-elem row (32 lanes x 4 elems): returns q0..q3.
__device__ __forceinline__ void cumq(float x0, float x1, float x2, float x3,
                                     bool row_head,
                                     float& q0, float& q1, float& q2, float& q3) {
    const float t0 = __cosf(x0), t1 = __cosf(x1);
    const float t2 = __cosf(x2), t3 = __cosf(x3);
    const float lp1 = t0 * t1, lp2 = lp1 * t2, lp3 = lp2 * t3;
    float sc = lp3;
    sc *= dppf<0x111, 0xF, F_ONE>(sc);   // row_shr:1
    sc *= dppf<0x112, 0xF, F_ONE>(sc);   // row_shr:2
    sc *= dppf<0x114, 0xF, F_ONE>(sc);   // row_shr:4
    sc *= dppf<0x118, 0xF, F_ONE>(sc);   // row_shr:8
    const float t15 = dppf<0x142, 0xA, F_ONE>(sc);  // bcast15 -> rows 1,3
    sc *= t15;                            // inclusive over 32-half
    float ex = dppf<0x111, 0xF, F_ONE>(sc);
    ex = row_head ? t15 : ex;             // heads: lane0/32 -> 1, lane16/48 -> t15
    q0 = ex * t0;  q1 = ex * lp1;
    q2 = ex * lp2; q3 = ex * lp3;
}

__device__ __forceinline__ void ln4(float y0, float y1, float y2, float y3,
                                    const float4 g, const float4 be,
                                    float& o0, float& o1, float& o2, float& o3) {
    const float s  = half_sum((y0 + y1) + (y2 + y3));
    const float s2 = half_sum(fmaf(y0, y0, y1 * y1) + fmaf(y2, y2, y3 * y3));
    const float mu  = s * (1.0f / 128.0f);
    const float var = fmaf(s2, 1.0f / 128.0f, -mu * mu);
    const float r   = rsqrtf(var + LN_EPS);
    o0 = fmaf((y0 - mu) * r, g.x, be.x);
    o1 = fmaf((y1 - mu) * r, g.y, be.y);
    o2 = fmaf((y2 - mu) * r, g.z, be.z);
    o3 = fmaf((y3 - mu) * r, g.w, be.w);
}

template <bool ATOMIC>
__global__ __launch_bounds__(256, 4) void qtc_main(
    const int*   __restrict__ tokens,   // [B, T]
    const float* __restrict__ emb,      // [V, E]
    const float* __restrict__ g1,       // [NBLK, E]
    const float* __restrict__ b1,
    const float* __restrict__ g2,
    const float* __restrict__ b2,
    float*       __restrict__ outp)     // ATOMIC: pooled[B,E]; else part[NUM_WG,E]
{
    __shared__ float part[WAVES_PER_WG][2][E_DIM];   // 4 KB

    const int lane = threadIdx.x & 63;
    const int wave = threadIdx.x >> 6;
    const int b    = blockIdx.x / WG_PER_B;
    const int wgb  = blockIdx.x % WG_PER_B;
    const int el   = lane & 31;         // element-group within row
    const int e0   = el * 4;            // first of 4 contiguous elems
    const int half = lane >> 5;         // which row of the wave's pair
    const int wid  = wgb * WAVES_PER_WG + wave;     // [0, 256) within batch
    const bool row_head = ((lane & 15) == 0);       // lanes 0,16,32,48

    // LN params: 16 float4 = 64 VGPRs
    float4 G1[NBLK], B1[NBLK], G2[NBLK], B2[NBLK];
    #pragma unroll
    for (int i = 0; i < NBLK; ++i) {
        G1[i] = *reinterpret_cast<const float4*>(&g1[i * E_DIM + e0]);
        B1[i] = *reinterpret_cast<const float4*>(&b1[i * E_DIM + e0]);
        G2[i] = *reinterpret_cast<const float4*>(&g2[i * E_DIM + e0]);
        B2[i] = *reinterpret_cast<const float4*>(&b2[i * E_DIM + e0]);
    }

    // PE freqs for elem pairs (e0,e0+1) and (e0+2,e0+3); native trig only.
    const float dfac0 = __expf(-(float)e0       * (9.210340371976184f / 128.0f));
    const float dfac1 = __expf(-(float)(e0 + 2) * (9.210340371976184f / 128.0f));
    const float tstA  = (float)(wid + 256 * half);
    const float tstB  = tstA + 512.0f;
    // chain A: tokens t, t+1024; chain B: tokens t+512, t+1536
    float pesA0 = __sinf(tstA * dfac0), pecA0 = __cosf(tstA * dfac0);
    float pesA1 = __sinf(tstA * dfac1), pecA1 = __cosf(tstA * dfac1);
    float pesB0 = __sinf(tstB * dfac0), pecB0 = __cosf(tstB * dfac0);
    float pesB1 = __sinf(tstB * dfac1), pecB1 = __cosf(tstB * dfac1);
    const float dS0 = __sinf(1024.0f * dfac0), dC0 = __cosf(1024.0f * dfac0);
    const float dS1 = __sinf(1024.0f * dfac1), dC1 = __cosf(1024.0f * dfac1);

    float sum0 = 0.0f, sum1 = 0.0f, sum2 = 0.0f, sum3 = 0.0f;
    int ix = b * T_LEN + wid + 256 * half;

    #pragma unroll
    for (int j = 0; j < 2; ++j) {
        const int tokA = tokens[ix];
        const int tokB = tokens[ix + 512];
        ix += 1024;
        const float4 xvA = *reinterpret_cast<const float4*>(&emb[tokA * E_DIM + e0]);
        const float4 xvB = *reinterpret_cast<const float4*>(&emb[tokB * E_DIM + e0]);
        float xA0 = xvA.x + pesA0, xA1 = xvA.y + pecA0;
        float xA2 = xvA.z + pesA1, xA3 = xvA.w + pecA1;
        float xB0 = xvB.x + pesB0, xB1 = xvB.y + pecB0;
        float xB2 = xvB.z + pesB1, xB3 = xvB.w + pecB1;
        // rotate both PE states forward by 1024 tokens (shared deltas)
        {
            float ns;
            ns = fmaf(pesA0, dC0,  pecA0 * dS0);
            pecA0 = fmaf(pecA0, dC0, -pesA0 * dS0); pesA0 = ns;
            ns = fmaf(pesA1, dC1,  pecA1 * dS1);
            pecA1 = fmaf(pecA1, dC1, -pesA1 * dS1); pesA1 = ns;
            ns = fmaf(pesB0, dC0,  pecB0 * dS0);
            pecB0 = fmaf(pecB0, dC0, -pesB0 * dS0); pesB0 = ns;
            ns = fmaf(pesB1, dC1,  pecB1 * dS1);
            pecB1 = fmaf(pecB1, dC1, -pesB1 * dS1); pesB1 = ns;
        }

        #pragma unroll
        for (int i = 0; i < NBLK; ++i) {
            float qA0, qA1, qA2, qA3, qB0, qB1, qB2, qB3;
            cumq(xA0, xA1, xA2, xA3, row_head, qA0, qA1, qA2, qA3);
            cumq(xB0, xB1, xB2, xB3, row_head, qB0, qB1, qB2, qB3);
            ln4(xA0 + qA0, xA1 + qA1, xA2 + qA2, xA3 + qA3, G1[i], B1[i],
                xA0, xA1, xA2, xA3);
            ln4(xB0 + qB0, xB1 + qB1, xB2 + qB2, xB3 + qB3, G1[i], B1[i],
                xB0, xB1, xB2, xB3);
            ln4(xA0 + qA0, xA1 + qA1, xA2 + qA2, xA3 + qA3, G2[i], B2[i],
                xA0, xA1, xA2, xA3);
            ln4(xB0 + qB0, xB1 + qB1, xB2 + qB2, xB3 + qB3, G2[i], B2[i],
                xB0, xB1, xB2, xB3);
        }
        sum0 += xA0 + xB0; sum1 += xA1 + xB1;
        sum2 += xA2 + xB2; sum3 += xA3 + xB3;
    }

    // block-level pooling: disjoint LDS writes, then one write per elem per WG
    float4* dst = reinterpret_cast<float4*>(&part[wave][half][e0]);
    *dst = make_float4(sum0, sum1, sum2, sum3);
    __syncthreads();
    if (threadIdx.x < E_DIM) {
        const int e = threadIdx.x;
        float s = 0.0f;
        #pragma unroll
        for (int w = 0; w < WAVES_PER_WG; ++w)
            s += part[w][0][e] + part[w][1][e];
        if (ATOMIC)
            atomicAdd(&outp[b * E_DIM + e], s);
        else
            outp[blockIdx.x * E_DIM + e] = s;   // disjoint partial row
    }
}

// Partials path: reduce 64 WG-partials per batch, then tiny matmul.
__global__ __launch_bounds__(64) void qtc_final_p(
    const float* __restrict__ part,    // [NUM_WG, E]
    const float* __restrict__ W,       // [E, C]
    const float* __restrict__ bias,    // [C]
    float*       __restrict__ out)     // [B, C]
{
    const int b    = blockIdx.x;       // one wave per batch element
    const int lane = threadIdx.x;
    const int e0   = 2 * lane;
    const float* base = part + (size_t)b * WG_PER_B * E_DIM + e0;
    float p0 = 0.0f, p1 = 0.0f;
    #pragma unroll 8
    for (int w = 0; w < WG_PER_B; ++w) {
        const float2 v = *reinterpret_cast<const float2*>(base + w * E_DIM);
        p0 += v.x; p1 += v.y;
    }
    float acc[C_CLS];
    #pragma unroll
    for (int c = 0; c < C_CLS; ++c)
        acc[c] = fmaf(p0, W[e0 * C_CLS + c], p1 * W[(e0 + 1) * C_CLS + c]);
    #pragma unroll
    for (int c = 0; c < C_CLS; ++c) {
        float s = acc[c];
        s = dpp_add<0x111, 0xF>(s);
        s = dpp_add<0x112, 0xF>(s);
        s = dpp_add<0x114, 0xF>(s);
        s = dpp_add<0x118, 0xF>(s);
        s = dpp_add<0x142, 0xA>(s);
        s = dpp_add<0x143, 0xC>(s);
        acc[c] = s;                    // total lives in lane 63
    }
    if (lane == 63) {
        #pragma unroll
        for (int c = 0; c < C_CLS; ++c)
            out[b * C_CLS + c] = fmaf(acc[c], 1.0f / (float)T_LEN, bias[c]);
    }
}

// Atomic-pooled fallback final (pooled[B,E] already summed).
__global__ __launch_bounds__(64) void qtc_final_a(
    const float* __restrict__ pooled,  // [B, E]
    const float* __restrict__ W,
    const float* __restrict__ bias,
    float*       __restrict__ out)
{
    const int b    = blockIdx.x;
    const int lane = threadIdx.x;
    const int e0   = 2 * lane;
    const float p0 = pooled[b * E_DIM + e0];
    const float p1 = pooled[b * E_DIM + e0 + 1];
    float acc[C_CLS];
    #pragma unroll
    for (int c = 0; c < C_CLS; ++c)
        acc[c] = fmaf(p0, W[e0 * C_CLS + c], p1 * W[(e0 + 1) * C_CLS + c]);
    #pragma unroll
    for (int c = 0; c < C_CLS; ++c) {
        float s = acc[c];
        s = dpp_add<0x111, 0xF>(s);
        s = dpp_add<0x112, 0xF>(s);
        s = dpp_add<0x114, 0xF>(s);
        s = dpp_add<0x118, 0xF>(s);
        s = dpp_add<0x142, 0xA>(s);
        s = dpp_add<0x143, 0xC>(s);
        acc[c] = s;
    }
    if (lane == 63) {
        #pragma unroll
        for (int c = 0; c < C_CLS; ++c)
            out[b * C_CLS + c] = fmaf(acc[c], 1.0f / (float)T_LEN, bias[c]);
    }
}

extern "C" void kernel_launch(void* const* d_in, const int* in_sizes, int n_in,
                              void* d_out, int out_size, void* d_ws, size_t ws_size,
                              hipStream_t stream) {
    const int*   tokens = (const int*)  d_in[0];
    const float* emb    = (const float*)d_in[1];
    const float* g1     = (const float*)d_in[2];
    const float* b1     = (const float*)d_in[3];
    const float* g2     = (const float*)d_in[4];
    const float* b2     = (const float*)d_in[5];
    // d_in[6] = q_weights: provably unused by the reference
    const float* W      = (const float*)d_in[7];
    const float* bias   = (const float*)d_in[8];
    float* out = (float*)d_out;

    const size_t part_bytes = (size_t)NUM_WG * E_DIM * sizeof(float);  // 1 MB
    if (ws_size >= part_bytes) {
        float* part = (float*)d_ws;
        qtc_main<false><<<NUM_WG, 256, 0, stream>>>(tokens, emb, g1, b1, g2, b2, part);
        qtc_final_p<<<B_SZ, 64, 0, stream>>>(part, W, bias, out);
    } else {
        float* pooled = (float*)d_ws;  // 16 KB
        hipMemsetAsync(pooled, 0, B_SZ * E_DIM * sizeof(float), stream);
        qtc_main<true><<<NUM_WG, 256, 0, stream>>>(tokens, emb, g1, b1, g2, b2, pooled);
        qtc_final_a<<<B_SZ, 64, 0, stream>>>(pooled, W, bias, out);
    }
}

// Round 7
// 30.476 us; speedup vs baseline: 5.0921x; 1.2357x over previous
//
#include <hip/hip_runtime.h>

// QuantumTextClassifier: embed+PE -> 4x {q=cumprod(cos(x)); x=LN(x+q); x=LN(x+q)}
// -> mean over T -> @W + b.
// Mapping: FOUR rows per wave (16 lanes/row, 8 elems/lane).
//  - cumprod scan: 4 DPP muls + 1 shr (16-lane rows align with DPP rows; heads
//    auto-get 1.0 via old-value semantics -> no patch select).
//  - LN sums: 4 fused DPP adds within the 16-lane row, result in all lanes.
//  - ZERO LDS-pipe ops in the hot loop (no ds_swizzle), all cross-lane = VALU.
//  - LN params loaded per block-iteration (non-unrolled NBLK loop) to avoid
//    128-VGPR param residency; L1-hot, latency hidden under cumq/reduce.
// Pooling: per-block LDS reduce -> disjoint partial row in d_ws (no atomics);
// qtc_final_p reduces 64 partials per batch + tiny matmul.

#define NBLK 4
#define E_DIM 128
#define T_LEN 2048
#define B_SZ 32
#define C_CLS 4
#define LN_EPS 1e-5f
#define WG_PER_B 64                         // workgroups per batch element
#define WAVES_PER_WG 4
#define NUM_WG (B_SZ * WG_PER_B)            // 2048

#define F_ONE 0x3F800000                    // bit pattern of 1.0f

// DPP move with old-value semantics (invalid/masked lanes -> OLD bits).
template <int CTRL, int RMASK, int OLDBITS>
__device__ __forceinline__ float dppf(float v) {
    return __int_as_float(__builtin_amdgcn_update_dpp(
        OLDBITS, __float_as_int(v), CTRL, RMASK, 0xF, false));
}

// Fused-add DPP step (bound_ctrl=1: invalid lanes contribute 0).
template <int CTRL>
__device__ __forceinline__ float dpp_add(float s) {
    return s + __int_as_float(__builtin_amdgcn_update_dpp(
        0, __float_as_int(s), CTRL, 0xF, 0xF, true));
}

// Sum over each 16-lane row; result broadcast to every lane of the row.
__device__ __forceinline__ float row16_sum(float s) {
    s = dpp_add<0xB1>(s);    // quad_perm [1,0,3,2]  ~ xor1
    s = dpp_add<0x4E>(s);    // quad_perm [2,3,0,1]  ~ xor2
    s = dpp_add<0x141>(s);   // row_half_mirror      ~ cross-quad within 8
    s = dpp_add<0x140>(s);   // row_mirror           ~ cross-8 within 16
    return s;
}

// LayerNorm over a 128-elem row held as 16 lanes x 8 elems.
__device__ __forceinline__ void ln8(const float* __restrict__ y,
                                    const float4 ga, const float4 gb,
                                    const float4 ba, const float4 bb,
                                    float* __restrict__ o) {
    const float s  = ((y[0] + y[1]) + (y[2] + y[3])) + ((y[4] + y[5]) + (y[6] + y[7]));
    const float a  = fmaf(y[1], y[1], y[0] * y[0]);
    const float b2 = fmaf(y[3], y[3], y[2] * y[2]);
    const float c  = fmaf(y[5], y[5], y[4] * y[4]);
    const float d  = fmaf(y[7], y[7], y[6] * y[6]);
    const float S  = row16_sum(s);
    const float S2 = row16_sum((a + b2) + (c + d));
    const float mu  = S * (1.0f / 128.0f);
    const float var = fmaf(S2, 1.0f / 128.0f, -mu * mu);
    const float r   = rsqrtf(var + LN_EPS);
    o[0] = fmaf((y[0] - mu) * r, ga.x, ba.x);
    o[1] = fmaf((y[1] - mu) * r, ga.y, ba.y);
    o[2] = fmaf((y[2] - mu) * r, ga.z, ba.z);
    o[3] = fmaf((y[3] - mu) * r, ga.w, ba.w);
    o[4] = fmaf((y[4] - mu) * r, gb.x, bb.x);
    o[5] = fmaf((y[5] - mu) * r, gb.y, bb.y);
    o[6] = fmaf((y[6] - mu) * r, gb.z, bb.z);
    o[7] = fmaf((y[7] - mu) * r, gb.w, bb.w);
}

__device__ __forceinline__ float4 ld4(const float* p) {
    return *reinterpret_cast<const float4*>(p);
}

template <bool ATOMIC>
__global__ __launch_bounds__(256, 4) void qtc_main(
    const int*   __restrict__ tokens,   // [B, T]
    const float* __restrict__ emb,      // [V, E]
    const float* __restrict__ g1,       // [NBLK, E]
    const float* __restrict__ b1,
    const float* __restrict__ g2,
    const float* __restrict__ b2,
    float*       __restrict__ outp)     // ATOMIC: pooled[B,E]; else part[NUM_WG,E]
{
    __shared__ float part[WAVES_PER_WG][4][E_DIM];   // 8 KB

    const int tid  = threadIdx.x;
    const int lane = tid & 63;
    const int wave = tid >> 6;
    const int b    = blockIdx.x / WG_PER_B;
    const int wgb  = blockIdx.x % WG_PER_B;
    const int row  = lane >> 4;          // which of the wave's 4 rows
    const int sub  = lane & 15;          // lane within row
    const int e0   = sub * 8;            // first of 8 contiguous elems
    const int wid  = wgb * WAVES_PER_WG + wave;     // [0, 256) within batch

    // Sinusoidal PE: elem pair (e0+2j, e0+2j+1) has freq f_j = 1e4^(-(e0+2j)/128).
    // Init at t0 (<1024 -> trig args within v_sin range), advance by 1024 via
    // angle-addition rotation (also in range).
    float pes[4], pec[4], dS[4], dC[4];
    {
        const float t0f = (float)(wid * 4 + row);
        #pragma unroll
        for (int j = 0; j < 4; ++j) {
            const float f = __expf(-(float)(e0 + 2 * j) * (9.210340371976184f / 128.0f));
            pes[j] = __sinf(t0f * f);
            pec[j] = __cosf(t0f * f);
            dS[j]  = __sinf(1024.0f * f);
            dC[j]  = __cosf(1024.0f * f);
        }
    }

    float sum[8];
    #pragma unroll
    for (int k = 0; k < 8; ++k) sum[k] = 0.0f;

    int tix = b * T_LEN + wid * 4 + row;

    #pragma unroll
    for (int it = 0; it < 2; ++it) {
        const int tok = tokens[tix];
        tix += 1024;
        const float4 v0 = ld4(&emb[tok * E_DIM + e0]);
        const float4 v1 = ld4(&emb[tok * E_DIM + e0 + 4]);
        float x[8];
        x[0] = v0.x + pes[0]; x[1] = v0.y + pec[0];
        x[2] = v0.z + pes[1]; x[3] = v0.w + pec[1];
        x[4] = v1.x + pes[2]; x[5] = v1.y + pec[2];
        x[6] = v1.z + pes[3]; x[7] = v1.w + pec[3];
        // rotate PE forward 1024 tokens
        #pragma unroll
        for (int j = 0; j < 4; ++j) {
            const float ns = fmaf(pes[j], dC[j],  pec[j] * dS[j]);
            pec[j]         = fmaf(pec[j], dC[j], -pes[j] * dS[j]);
            pes[j]         = ns;
        }

        #pragma unroll 1   // keep param loads inside (prevents 128-reg hoist)
        for (int i = 0; i < NBLK; ++i) {
            const float* gp1 = g1 + i * E_DIM + e0;
            const float* bp1 = b1 + i * E_DIM + e0;
            const float* gp2 = g2 + i * E_DIM + e0;
            const float* bp2 = b2 + i * E_DIM + e0;
            const float4 G1a = ld4(gp1), G1b = ld4(gp1 + 4);
            const float4 B1a = ld4(bp1), B1b = ld4(bp1 + 4);
            const float4 G2a = ld4(gp2), G2b = ld4(gp2 + 4);
            const float4 B2a = ld4(bp2), B2b = ld4(bp2 + 4);

            // cumprod(cos(x)) along the row: local prefixes + 16-lane DPP scan
            const float c0 = __cosf(x[0]), c1 = __cosf(x[1]);
            const float c2 = __cosf(x[2]), c3 = __cosf(x[3]);
            const float c4 = __cosf(x[4]), c5 = __cosf(x[5]);
            const float c6 = __cosf(x[6]), c7 = __cosf(x[7]);
            const float p01 = c0 * c1, p23 = c2 * c3, p45 = c4 * c5, p67 = c6 * c7;
            const float l03 = p01 * p23, l47 = p45 * p67;
            const float tot = l03 * l47;          // lane's 8-elem product
            float sc = tot;                       // inclusive scan over 16 lanes
            sc *= dppf<0x111, 0xF, F_ONE>(sc);    // row_shr:1
            sc *= dppf<0x112, 0xF, F_ONE>(sc);    // row_shr:2
            sc *= dppf<0x114, 0xF, F_ONE>(sc);    // row_shr:4
            sc *= dppf<0x118, 0xF, F_ONE>(sc);    // row_shr:8
            // exclusive: shift by 1; row-head lanes auto-get old=1.0
            const float ex = dppf<0x111, 0xF, F_ONE>(sc);
            // per-elem inclusive prefixes
            float q[8];
            q[0] = ex * c0;
            q[1] = ex * p01;
            q[2] = ex * (p01 * c2);
            q[3] = ex * l03;
            q[4] = ex * (l03 * c4);
            q[5] = ex * (l03 * p45);
            q[6] = ex * ((l03 * p45) * c6);
            q[7] = ex * tot;

            float y[8];
            #pragma unroll
            for (int k = 0; k < 8; ++k) y[k] = x[k] + q[k];
            ln8(y, G1a, G1b, B1a, B1b, x);
            #pragma unroll
            for (int k = 0; k < 8; ++k) y[k] = x[k] + q[k];
            ln8(y, G2a, G2b, B2a, B2b, x);
        }
        #pragma unroll
        for (int k = 0; k < 8; ++k) sum[k] += x[k];
    }

    // block-level pooling: disjoint LDS writes, then one write per elem per WG
    *reinterpret_cast<float4*>(&part[wave][row][e0])     =
        make_float4(sum[0], sum[1], sum[2], sum[3]);
    *reinterpret_cast<float4*>(&part[wave][row][e0 + 4]) =
        make_float4(sum[4], sum[5], sum[6], sum[7]);
    __syncthreads();
    if (tid < E_DIM) {
        float s = 0.0f;
        #pragma unroll
        for (int w = 0; w < WAVES_PER_WG; ++w)
            #pragma unroll
            for (int r = 0; r < 4; ++r)
                s += part[w][r][tid];
        if (ATOMIC)
            atomicAdd(&outp[b * E_DIM + tid], s);
        else
            outp[blockIdx.x * E_DIM + tid] = s;   // disjoint partial row
    }
}

// Fused-add DPP over full wave (for the final reduce kernel).
__device__ __forceinline__ float wave_sum_tail(float s) {
    s = dpp_add<0xB1>(s);
    s = dpp_add<0x4E>(s);
    s = dpp_add<0x141>(s);
    s = dpp_add<0x140>(s);
    s = s + __int_as_float(__builtin_amdgcn_update_dpp(
        0, __float_as_int(s), 0x142, 0xA, 0xF, true));   // row_bcast15 -> rows 1,3
    s = s + __int_as_float(__builtin_amdgcn_update_dpp(
        0, __float_as_int(s), 0x143, 0xC, 0xF, true));   // row_bcast31 -> rows 2,3
    return s;                                            // total in lane 63
}

// Partials path: reduce 64 WG-partials per batch, then tiny matmul.
__global__ __launch_bounds__(64) void qtc_final_p(
    const float* __restrict__ part,    // [NUM_WG, E]
    const float* __restrict__ W,       // [E, C]
    const float* __restrict__ bias,    // [C]
    float*       __restrict__ out)     // [B, C]
{
    const int b    = blockIdx.x;       // one wave per batch element
    const int lane = threadIdx.x;
    const int e0   = 2 * lane;
    const float* base = part + (size_t)b * WG_PER_B * E_DIM + e0;
    float p0 = 0.0f, p1 = 0.0f;
    #pragma unroll 8
    for (int w = 0; w < WG_PER_B; ++w) {
        const float2 v = *reinterpret_cast<const float2*>(base + w * E_DIM);
        p0 += v.x; p1 += v.y;
    }
    float acc[C_CLS];
    #pragma unroll
    for (int c = 0; c < C_CLS; ++c)
        acc[c] = fmaf(p0, W[e0 * C_CLS + c], p1 * W[(e0 + 1) * C_CLS + c]);
    #pragma unroll
    for (int c = 0; c < C_CLS; ++c)
        acc[c] = wave_sum_tail(acc[c]);
    if (lane == 63) {
        #pragma unroll
        for (int c = 0; c < C_CLS; ++c)
            out[b * C_CLS + c] = fmaf(acc[c], 1.0f / (float)T_LEN, bias[c]);
    }
}

// Atomic-pooled fallback final (pooled[B,E] already summed).
__global__ __launch_bounds__(64) void qtc_final_a(
    const float* __restrict__ pooled,  // [B, E]
    const float* __restrict__ W,
    const float* __restrict__ bias,
    float*       __restrict__ out)
{
    const int b    = blockIdx.x;
    const int lane = threadIdx.x;
    const int e0   = 2 * lane;
    const float p0 = pooled[b * E_DIM + e0];
    const float p1 = pooled[b * E_DIM + e0 + 1];
    float acc[C_CLS];
    #pragma unroll
    for (int c = 0; c < C_CLS; ++c)
        acc[c] = fmaf(p0, W[e0 * C_CLS + c], p1 * W[(e0 + 1) * C_CLS + c]);
    #pragma unroll
    for (int c = 0; c < C_CLS; ++c)
        acc[c] = wave_sum_tail(acc[c]);
    if (lane == 63) {
        #pragma unroll
        for (int c = 0; c < C_CLS; ++c)
            out[b * C_CLS + c] = fmaf(acc[c], 1.0f / (float)T_LEN, bias[c]);
    }
}

extern "C" void kernel_launch(void* const* d_in, const int* in_sizes, int n_in,
                              void* d_out, int out_size, void* d_ws, size_t ws_size,
                              hipStream_t stream) {
    const int*   tokens = (const int*)  d_in[0];
    const float* emb    = (const float*)d_in[1];
    const float* g1     = (const float*)d_in[2];
    const float* b1     = (const float*)d_in[3];
    const float* g2     = (const float*)d_in[4];
    const float* b2     = (const float*)d_in[5];
    // d_in[6] = q_weights: provably unused by the reference
    const float* W      = (const float*)d_in[7];
    const float* bias   = (const float*)d_in[8];
    float* out = (float*)d_out;

    const size_t part_bytes = (size_t)NUM_WG * E_DIM * sizeof(float);  // 1 MB
    if (ws_size >= part_bytes) {
        float* part = (float*)d_ws;
        qtc_main<false><<<NUM_WG, 256, 0, stream>>>(tokens, emb, g1, b1, g2, b2, part);
        qtc_final_p<<<B_SZ, 64, 0, stream>>>(part, W, bias, out);
    } else {
        float* pooled = (float*)d_ws;  // 16 KB
        hipMemsetAsync(pooled, 0, B_SZ * E_DIM * sizeof(float), stream);
        qtc_main<true><<<NUM_WG, 256, 0, stream>>>(tokens, emb, g1, b1, g2, b2, pooled);
        qtc_final_a<<<B_SZ, 64, 0, stream>>>(pooled, W, bias, out);
    }
}

// Round 8
// 28.950 us; speedup vs baseline: 5.3604x; 1.0527x over previous
//
#include <hip/hip_runtime.h>

// QuantumTextClassifier: embed+PE -> 4x {q=cumprod(cos(x)); x=LN(x+q); x=LN(x+q)}
// -> mean over T -> @W + b.
// Mapping: FOUR rows per wave (16 lanes/row, 8 elems/lane = 4x float2).
//  - Elementwise math in ext_vector float2 -> v_pk_{add,mul,fma}_f32 (2 flops/
//    lane/instr on gfx950 packed-FP32 pipe) ~ halves elementwise VALU count.
//  - cumprod scan: 4 DPP muls + 1 shr (16-lane rows align with DPP rows).
//  - LN sums: 4 fused DPP adds within the row; zero LDS-pipe ops in hot loop.
//  - LN params loaded per block-iteration (non-unrolled NBLK loop).
// Pooling: per-block LDS reduce -> disjoint partial row in d_ws (no atomics);
// qtc_final_p reduces 64 partials per batch + tiny matmul.

#define NBLK 4
#define E_DIM 128
#define T_LEN 2048
#define B_SZ 32
#define C_CLS 4
#define LN_EPS 1e-5f
#define WG_PER_B 64                         // workgroups per batch element
#define WAVES_PER_WG 4
#define NUM_WG (B_SZ * WG_PER_B)            // 2048

#define F_ONE 0x3F800000                    // bit pattern of 1.0f

typedef float v2f __attribute__((ext_vector_type(2)));
typedef float v4f __attribute__((ext_vector_type(4)));

// DPP move with old-value semantics (invalid/masked lanes -> OLD bits).
template <int CTRL, int RMASK, int OLDBITS>
__device__ __forceinline__ float dppf(float v) {
    return __int_as_float(__builtin_amdgcn_update_dpp(
        OLDBITS, __float_as_int(v), CTRL, RMASK, 0xF, false));
}

// Fused-add DPP step (bound_ctrl=1: invalid lanes contribute 0).
template <int CTRL>
__device__ __forceinline__ float dpp_add(float s) {
    return s + __int_as_float(__builtin_amdgcn_update_dpp(
        0, __float_as_int(s), CTRL, 0xF, 0xF, true));
}

// Sum over each 16-lane row; result broadcast to every lane of the row.
__device__ __forceinline__ float row16_sum(float s) {
    s = dpp_add<0xB1>(s);    // quad_perm [1,0,3,2]  ~ xor1
    s = dpp_add<0x4E>(s);    // quad_perm [2,3,0,1]  ~ xor2
    s = dpp_add<0x141>(s);   // row_half_mirror      ~ xor4
    s = dpp_add<0x140>(s);   // row_mirror           ~ xor8
    return s;
}

__device__ __forceinline__ v4f ld4(const float* p) {
    return *reinterpret_cast<const v4f*>(p);
}

// LayerNorm over a 128-elem row held as 16 lanes x 4 float2.
__device__ __forceinline__ void ln8v(const v2f* __restrict__ Y,
                                     const v2f* __restrict__ g,
                                     const v2f* __restrict__ be,
                                     v2f* __restrict__ o) {
    v2f sv = (Y[0] + Y[1]) + (Y[2] + Y[3]);
    v2f qv = Y[0] * Y[0];
    qv = __builtin_elementwise_fma(Y[1], Y[1], qv);
    qv = __builtin_elementwise_fma(Y[2], Y[2], qv);
    qv = __builtin_elementwise_fma(Y[3], Y[3], qv);
    const float S  = row16_sum(sv.x + sv.y);
    const float S2 = row16_sum(qv.x + qv.y);
    const float mu  = S * (1.0f / 128.0f);
    const float var = fmaf(S2, 1.0f / 128.0f, -mu * mu);
    const float r   = rsqrtf(var + LN_EPS);
    const v2f muv = {mu, mu};
    const v2f rv  = {r, r};
    #pragma unroll
    for (int j = 0; j < 4; ++j)
        o[j] = __builtin_elementwise_fma((Y[j] - muv) * rv, g[j], be[j]);
}

template <bool ATOMIC>
__global__ __launch_bounds__(256, 4) void qtc_main(
    const int*   __restrict__ tokens,   // [B, T]
    const float* __restrict__ emb,      // [V, E]
    const float* __restrict__ g1,       // [NBLK, E]
    const float* __restrict__ b1,
    const float* __restrict__ g2,
    const float* __restrict__ b2,
    float*       __restrict__ outp)     // ATOMIC: pooled[B,E]; else part[NUM_WG,E]
{
    __shared__ float part[WAVES_PER_WG][4][E_DIM];   // 8 KB

    const int tid  = threadIdx.x;
    const int lane = tid & 63;
    const int wave = tid >> 6;
    const int b    = blockIdx.x / WG_PER_B;
    const int wgb  = blockIdx.x % WG_PER_B;
    const int row  = lane >> 4;          // which of the wave's 4 rows
    const int sub  = lane & 15;          // lane within row
    const int e0   = sub * 8;            // first of 8 contiguous elems
    const int wid  = wgb * WAVES_PER_WG + wave;     // [0, 256) within batch

    // Sinusoidal PE: elem pair (e0+2j, e0+2j+1) has freq f_j = 1e4^(-(e0+2j)/128).
    // PE state packed as (sin, cos) float2 per pair; advance by 1024 tokens via
    // angle-addition rotation.
    v2f PE[4];
    float dS[4], dC[4];
    {
        const float t0f = (float)(wid * 4 + row);
        #pragma unroll
        for (int j = 0; j < 4; ++j) {
            const float f = __expf(-(float)(e0 + 2 * j) * (9.210340371976184f / 128.0f));
            PE[j] = (v2f){__sinf(t0f * f), __cosf(t0f * f)};
            dS[j] = __sinf(1024.0f * f);
            dC[j] = __cosf(1024.0f * f);
        }
    }

    v2f Sm[4] = {(v2f)0.0f, (v2f)0.0f, (v2f)0.0f, (v2f)0.0f};
    int tix = b * T_LEN + wid * 4 + row;

    #pragma unroll
    for (int it = 0; it < 2; ++it) {
        const int tok = tokens[tix];
        tix += 1024;
        const v4f v0 = ld4(&emb[tok * E_DIM + e0]);
        const v4f v1 = ld4(&emb[tok * E_DIM + e0 + 4]);
        v2f X[4];
        X[0] = v0.xy + PE[0]; X[1] = v0.zw + PE[1];
        X[2] = v1.xy + PE[2]; X[3] = v1.zw + PE[3];
        // rotate PE forward 1024 tokens
        #pragma unroll
        for (int j = 0; j < 4; ++j) {
            const float s = PE[j].x, c = PE[j].y;
            PE[j] = (v2f){fmaf(s, dC[j],  c * dS[j]),
                          fmaf(c, dC[j], -s * dS[j])};
        }

        #pragma unroll 1   // keep param loads inside (prevents full-param hoist)
        for (int i = 0; i < NBLK; ++i) {
            const float* gp1 = g1 + i * E_DIM + e0;
            const float* bp1 = b1 + i * E_DIM + e0;
            const float* gp2 = g2 + i * E_DIM + e0;
            const float* bp2 = b2 + i * E_DIM + e0;
            const v4f G1a = ld4(gp1), G1b = ld4(gp1 + 4);
            const v4f B1a = ld4(bp1), B1b = ld4(bp1 + 4);
            const v4f G2a = ld4(gp2), G2b = ld4(gp2 + 4);
            const v4f B2a = ld4(bp2), B2b = ld4(bp2 + 4);
            const v2f g1v[4] = {G1a.xy, G1a.zw, G1b.xy, G1b.zw};
            const v2f b1v[4] = {B1a.xy, B1a.zw, B1b.xy, B1b.zw};
            const v2f g2v[4] = {G2a.xy, G2a.zw, G2b.xy, G2b.zw};
            const v2f b2v[4] = {B2a.xy, B2a.zw, B2b.xy, B2b.zw};

            // cumprod(cos(x)) along the row: local prefixes + 16-lane DPP scan
            const float c0 = __cosf(X[0].x), c1 = __cosf(X[0].y);
            const float c2 = __cosf(X[1].x), c3 = __cosf(X[1].y);
            const float c4 = __cosf(X[2].x), c5 = __cosf(X[2].y);
            const float c6 = __cosf(X[3].x), c7 = __cosf(X[3].y);
            const float p23 = c2 * c3, p45 = c4 * c5, p67 = c6 * c7;
            const float P2 = c0 * c1;
            const float P4 = P2 * p23;
            const float P6 = P4 * p45;
            const float P8 = P6 * p67;         // lane's 8-elem product
            const float P3 = P2 * c2;
            const float P5 = P4 * c4;
            const float P7 = P6 * c6;
            float sc = P8;                     // inclusive scan over 16 lanes
            sc *= dppf<0x111, 0xF, F_ONE>(sc); // row_shr:1
            sc *= dppf<0x112, 0xF, F_ONE>(sc); // row_shr:2
            sc *= dppf<0x114, 0xF, F_ONE>(sc); // row_shr:4
            sc *= dppf<0x118, 0xF, F_ONE>(sc); // row_shr:8
            // exclusive: shift by 1; row-head lanes auto-get old=1.0
            const float ex = dppf<0x111, 0xF, F_ONE>(sc);
            const v2f exv = {ex, ex};
            v2f Q[4];
            Q[0] = exv * (v2f){c0, P2};
            Q[1] = exv * (v2f){P3, P4};
            Q[2] = exv * (v2f){P5, P6};
            Q[3] = exv * (v2f){P7, P8};

            v2f Y[4];
            #pragma unroll
            for (int k = 0; k < 4; ++k) Y[k] = X[k] + Q[k];
            ln8v(Y, g1v, b1v, X);
            #pragma unroll
            for (int k = 0; k < 4; ++k) Y[k] = X[k] + Q[k];
            ln8v(Y, g2v, b2v, X);
        }
        #pragma unroll
        for (int k = 0; k < 4; ++k) Sm[k] += X[k];
    }

    // block-level pooling: disjoint LDS writes, then one write per elem per WG
    const v4f lo = {Sm[0].x, Sm[0].y, Sm[1].x, Sm[1].y};
    const v4f hi = {Sm[2].x, Sm[2].y, Sm[3].x, Sm[3].y};
    *reinterpret_cast<v4f*>(&part[wave][row][e0])     = lo;
    *reinterpret_cast<v4f*>(&part[wave][row][e0 + 4]) = hi;
    __syncthreads();
    if (tid < E_DIM) {
        float s = 0.0f;
        #pragma unroll
        for (int w = 0; w < WAVES_PER_WG; ++w)
            #pragma unroll
            for (int r = 0; r < 4; ++r)
                s += part[w][r][tid];
        if (ATOMIC)
            atomicAdd(&outp[b * E_DIM + tid], s);
        else
            outp[blockIdx.x * E_DIM + tid] = s;   // disjoint partial row
    }
}

// Fused-add DPP over full wave (for the final reduce kernels).
__device__ __forceinline__ float wave_sum_tail(float s) {
    s = dpp_add<0xB1>(s);
    s = dpp_add<0x4E>(s);
    s = dpp_add<0x141>(s);
    s = dpp_add<0x140>(s);
    s = s + __int_as_float(__builtin_amdgcn_update_dpp(
        0, __float_as_int(s), 0x142, 0xA, 0xF, true));   // row_bcast15 -> rows 1,3
    s = s + __int_as_float(__builtin_amdgcn_update_dpp(
        0, __float_as_int(s), 0x143, 0xC, 0xF, true));   // row_bcast31 -> rows 2,3
    return s;                                            // total in lane 63
}

// Partials path: reduce 64 WG-partials per batch, then tiny matmul.
__global__ __launch_bounds__(64) void qtc_final_p(
    const float* __restrict__ part,    // [NUM_WG, E]
    const float* __restrict__ W,       // [E, C]
    const float* __restrict__ bias,    // [C]
    float*       __restrict__ out)     // [B, C]
{
    const int b    = blockIdx.x;       // one wave per batch element
    const int lane = threadIdx.x;
    const int e0   = 2 * lane;
    const float* base = part + (size_t)b * WG_PER_B * E_DIM + e0;
    float p0 = 0.0f, p1 = 0.0f;
    #pragma unroll 8
    for (int w = 0; w < WG_PER_B; ++w) {
        const float2 v = *reinterpret_cast<const float2*>(base + w * E_DIM);
        p0 += v.x; p1 += v.y;
    }
    float acc[C_CLS];
    #pragma unroll
    for (int c = 0; c < C_CLS; ++c)
        acc[c] = fmaf(p0, W[e0 * C_CLS + c], p1 * W[(e0 + 1) * C_CLS + c]);
    #pragma unroll
    for (int c = 0; c < C_CLS; ++c)
        acc[c] = wave_sum_tail(acc[c]);
    if (lane == 63) {
        #pragma unroll
        for (int c = 0; c < C_CLS; ++c)
            out[b * C_CLS + c] = fmaf(acc[c], 1.0f / (float)T_LEN, bias[c]);
    }
}

// Atomic-pooled fallback final (pooled[B,E] already summed).
__global__ __launch_bounds__(64) void qtc_final_a(
    const float* __restrict__ pooled,  // [B, E]
    const float* __restrict__ W,
    const float* __restrict__ bias,
    float*       __restrict__ out)
{
    const int b    = blockIdx.x;
    const int lane = threadIdx.x;
    const int e0   = 2 * lane;
    const float p0 = pooled[b * E_DIM + e0];
    const float p1 = pooled[b * E_DIM + e0 + 1];
    float acc[C_CLS];
    #pragma unroll
    for (int c = 0; c < C_CLS; ++c)
        acc[c] = fmaf(p0, W[e0 * C_CLS + c], p1 * W[(e0 + 1) * C_CLS + c]);
    #pragma unroll
    for (int c = 0; c < C_CLS; ++c)
        acc[c] = wave_sum_tail(acc[c]);
    if (lane == 63) {
        #pragma unroll
        for (int c = 0; c < C_CLS; ++c)
            out[b * C_CLS + c] = fmaf(acc[c], 1.0f / (float)T_LEN, bias[c]);
    }
}

extern "C" void kernel_launch(void* const* d_in, const int* in_sizes, int n_in,
                              void* d_out, int out_size, void* d_ws, size_t ws_size,
                              hipStream_t stream) {
    const int*   tokens = (const int*)  d_in[0];
    const float* emb    = (const float*)d_in[1];
    const float* g1     = (const float*)d_in[2];
    const float* b1     = (const float*)d_in[3];
    const float* g2     = (const float*)d_in[4];
    const float* b2     = (const float*)d_in[5];
    // d_in[6] = q_weights: provably unused by the reference
    const float* W      = (const float*)d_in[7];
    const float* bias   = (const float*)d_in[8];
    float* out = (float*)d_out;

    const size_t part_bytes = (size_t)NUM_WG * E_DIM * sizeof(float);  // 1 MB
    if (ws_size >= part_bytes) {
        float* part = (float*)d_ws;
        qtc_main<false><<<NUM_WG, 256, 0, stream>>>(tokens, emb, g1, b1, g2, b2, part);
        qtc_final_p<<<B_SZ, 64, 0, stream>>>(part, W, bias, out);
    } else {
        float* pooled = (float*)d_ws;  // 16 KB
        hipMemsetAsync(pooled, 0, B_SZ * E_DIM * sizeof(float), stream);
        qtc_main<true><<<NUM_WG, 256, 0, stream>>>(tokens, emb, g1, b1, g2, b2, pooled);
        qtc_final_a<<<B_SZ, 64, 0, stream>>>(pooled, W, bias, out);
    }
}

// Round 9
// 28.208 us; speedup vs baseline: 5.5015x; 1.0263x over previous
//
#include <hip/hip_runtime.h>

// QuantumTextClassifier: embed+PE -> 4x {q=cumprod(cos(x)); x=LN(x+q); x=LN(x+q)}
// -> mean over T -> @W + b.
// Mapping: FOUR rows per wave (16 lanes/row, 8 elems/lane = 4x float2).
//  - ALL LN params (128 floats = 64 VGPR) hoisted to registers once; NBLK loop
//    fully unrolled -> ZERO VMEM inside the hot chain.
//  - The wave's 2 tokens run as two independent chains through the unrolled
//    body (chain ILP x2), PE computed directly per position (no rotation).
//  - cumprod scan: 4 DPP muls + 1 shr; LN sums: 4 fused DPP adds; all
//    cross-lane on the VALU pipe (no LDS ops in hot loop).
// Pooling: per-block LDS reduce -> disjoint partial row in d_ws (no atomics);
// qtc_final_p (256 thr, split w-loop) reduces 64 partials/batch + tiny matmul.

#define NBLK 4
#define E_DIM 128
#define T_LEN 2048
#define B_SZ 32
#define C_CLS 4
#define LN_EPS 1e-5f
#define WG_PER_B 64                         // workgroups per batch element
#define WAVES_PER_WG 4
#define NUM_WG (B_SZ * WG_PER_B)            // 2048

#define F_ONE 0x3F800000                    // bit pattern of 1.0f

typedef float v2f __attribute__((ext_vector_type(2)));
typedef float v4f __attribute__((ext_vector_type(4)));

// DPP move with old-value semantics (invalid/masked lanes -> OLD bits).
template <int CTRL, int RMASK, int OLDBITS>
__device__ __forceinline__ float dppf(float v) {
    return __int_as_float(__builtin_amdgcn_update_dpp(
        OLDBITS, __float_as_int(v), CTRL, RMASK, 0xF, false));
}

// Fused-add DPP step (bound_ctrl=1: invalid lanes contribute 0).
template <int CTRL>
__device__ __forceinline__ float dpp_add(float s) {
    return s + __int_as_float(__builtin_amdgcn_update_dpp(
        0, __float_as_int(s), CTRL, 0xF, 0xF, true));
}

// Sum over each 16-lane row; result broadcast to every lane of the row.
__device__ __forceinline__ float row16_sum(float s) {
    s = dpp_add<0xB1>(s);    // quad_perm [1,0,3,2]  ~ xor1
    s = dpp_add<0x4E>(s);    // quad_perm [2,3,0,1]  ~ xor2
    s = dpp_add<0x141>(s);   // row_half_mirror      ~ xor4
    s = dpp_add<0x140>(s);   // row_mirror           ~ xor8
    return s;
}

__device__ __forceinline__ v4f ld4(const float* p) {
    return *reinterpret_cast<const v4f*>(p);
}

// cumprod(cos(X)) along the 128-elem row (16 lanes x 4 v2f): Q = prefix prods.
__device__ __forceinline__ void cumq_v(const v2f* __restrict__ X,
                                       v2f* __restrict__ Q) {
    const float c0 = __cosf(X[0].x), c1 = __cosf(X[0].y);
    const float c2 = __cosf(X[1].x), c3 = __cosf(X[1].y);
    const float c4 = __cosf(X[2].x), c5 = __cosf(X[2].y);
    const float c6 = __cosf(X[3].x), c7 = __cosf(X[3].y);
    const float p23 = c2 * c3, p45 = c4 * c5, p67 = c6 * c7;
    const float P2 = c0 * c1;
    const float P4 = P2 * p23;
    const float P6 = P4 * p45;
    const float P8 = P6 * p67;         // lane's 8-elem product
    const float P3 = P2 * c2;
    const float P5 = P4 * c4;
    const float P7 = P6 * c6;
    float sc = P8;                     // inclusive scan over 16 lanes
    sc *= dppf<0x111, 0xF, F_ONE>(sc); // row_shr:1
    sc *= dppf<0x112, 0xF, F_ONE>(sc); // row_shr:2
    sc *= dppf<0x114, 0xF, F_ONE>(sc); // row_shr:4
    sc *= dppf<0x118, 0xF, F_ONE>(sc); // row_shr:8
    // exclusive: shift by 1; row-head lanes auto-get old=1.0
    const float ex = dppf<0x111, 0xF, F_ONE>(sc);
    const v2f exv = {ex, ex};
    Q[0] = exv * (v2f){c0, P2};
    Q[1] = exv * (v2f){P3, P4};
    Q[2] = exv * (v2f){P5, P6};
    Q[3] = exv * (v2f){P7, P8};
}

// LayerNorm over a 128-elem row held as 16 lanes x 4 float2.
__device__ __forceinline__ void ln8v(const v2f* __restrict__ Y,
                                     const v2f* __restrict__ g,
                                     const v2f* __restrict__ be,
                                     v2f* __restrict__ o) {
    v2f sv = (Y[0] + Y[1]) + (Y[2] + Y[3]);
    v2f qv = Y[0] * Y[0];
    qv = __builtin_elementwise_fma(Y[1], Y[1], qv);
    qv = __builtin_elementwise_fma(Y[2], Y[2], qv);
    qv = __builtin_elementwise_fma(Y[3], Y[3], qv);
    const float S  = row16_sum(sv.x + sv.y);
    const float S2 = row16_sum(qv.x + qv.y);
    const float mu  = S * (1.0f / 128.0f);
    const float var = fmaf(S2, 1.0f / 128.0f, -mu * mu);
    const float r   = rsqrtf(var + LN_EPS);
    const v2f muv = {mu, mu};
    const v2f rv  = {r, r};
    #pragma unroll
    for (int j = 0; j < 4; ++j)
        o[j] = __builtin_elementwise_fma((Y[j] - muv) * rv, g[j], be[j]);
}

template <bool ATOMIC>
__global__ __launch_bounds__(256, 4) void qtc_main(
    const int*   __restrict__ tokens,   // [B, T]
    const float* __restrict__ emb,      // [V, E]
    const float* __restrict__ g1,       // [NBLK, E]
    const float* __restrict__ b1,
    const float* __restrict__ g2,
    const float* __restrict__ b2,
    float*       __restrict__ outp)     // ATOMIC: pooled[B,E]; else part[NUM_WG,E]
{
    __shared__ float part[WAVES_PER_WG][4][E_DIM];   // 8 KB

    const int tid  = threadIdx.x;
    const int lane = tid & 63;
    const int wave = tid >> 6;
    const int b    = blockIdx.x / WG_PER_B;
    const int wgb  = blockIdx.x % WG_PER_B;
    const int row  = lane >> 4;          // which of the wave's 4 rows
    const int sub  = lane & 15;          // lane within row
    const int e0   = sub * 8;            // first of 8 contiguous elems
    const int wid  = wgb * WAVES_PER_WG + wave;     // [0, 256) within batch

    // ---- hoist ALL LN params into registers (64 VGPR) ----
    v2f G1[NBLK][4], B1[NBLK][4], G2[NBLK][4], B2[NBLK][4];
    #pragma unroll
    for (int i = 0; i < NBLK; ++i) {
        const v4f a1 = ld4(g1 + i * E_DIM + e0), a2 = ld4(g1 + i * E_DIM + e0 + 4);
        const v4f c1v = ld4(b1 + i * E_DIM + e0), c2v = ld4(b1 + i * E_DIM + e0 + 4);
        const v4f d1 = ld4(g2 + i * E_DIM + e0), d2 = ld4(g2 + i * E_DIM + e0 + 4);
        const v4f e1 = ld4(b2 + i * E_DIM + e0), e2 = ld4(b2 + i * E_DIM + e0 + 4);
        G1[i][0] = a1.xy;  G1[i][1] = a1.zw;  G1[i][2] = a2.xy;  G1[i][3] = a2.zw;
        B1[i][0] = c1v.xy; B1[i][1] = c1v.zw; B1[i][2] = c2v.xy; B1[i][3] = c2v.zw;
        G2[i][0] = d1.xy;  G2[i][1] = d1.zw;  G2[i][2] = d2.xy;  G2[i][3] = d2.zw;
        B2[i][0] = e1.xy;  B2[i][1] = e1.zw;  B2[i][2] = e2.xy;  B2[i][3] = e2.zw;
    }

    // ---- two token positions, PE computed directly (no rotation state) ----
    const int   ta  = wid * 4 + row;           // token index A (< 1024)
    const int   tix = b * T_LEN + ta;
    const int   tokA = tokens[tix];
    const int   tokB = tokens[tix + 1024];
    const float tfA = (float)ta;
    const float tfB = (float)(ta + 1024);

    v2f Xa[4], Xb[4];
    {
        const v4f a0 = ld4(&emb[tokA * E_DIM + e0]);
        const v4f a1 = ld4(&emb[tokA * E_DIM + e0 + 4]);
        const v4f b0 = ld4(&emb[tokB * E_DIM + e0]);
        const v4f b1v = ld4(&emb[tokB * E_DIM + e0 + 4]);
        const v2f ea[4] = {a0.xy, a0.zw, a1.xy, a1.zw};
        const v2f eb[4] = {b0.xy, b0.zw, b1v.xy, b1v.zw};
        #pragma unroll
        for (int j = 0; j < 4; ++j) {
            const float f = __expf(-(float)(e0 + 2 * j) * (9.210340371976184f / 128.0f));
            Xa[j] = ea[j] + (v2f){__sinf(tfA * f), __cosf(tfA * f)};
            Xb[j] = eb[j] + (v2f){__sinf(tfB * f), __cosf(tfB * f)};
        }
    }

    // ---- 4 transformer-sim blocks, two independent chains (A,B) ----
    #pragma unroll
    for (int i = 0; i < NBLK; ++i) {
        v2f Qa[4], Qb[4], Y[4];
        cumq_v(Xa, Qa);
        cumq_v(Xb, Qb);
        #pragma unroll
        for (int k = 0; k < 4; ++k) Y[k] = Xa[k] + Qa[k];
        ln8v(Y, G1[i], B1[i], Xa);
        #pragma unroll
        for (int k = 0; k < 4; ++k) Y[k] = Xb[k] + Qb[k];
        ln8v(Y, G1[i], B1[i], Xb);
        #pragma unroll
        for (int k = 0; k < 4; ++k) Y[k] = Xa[k] + Qa[k];
        ln8v(Y, G2[i], B2[i], Xa);
        #pragma unroll
        for (int k = 0; k < 4; ++k) Y[k] = Xb[k] + Qb[k];
        ln8v(Y, G2[i], B2[i], Xb);
    }

    // ---- block-level pooling ----
    const v4f lo = {Xa[0].x + Xb[0].x, Xa[0].y + Xb[0].y,
                    Xa[1].x + Xb[1].x, Xa[1].y + Xb[1].y};
    const v4f hi = {Xa[2].x + Xb[2].x, Xa[2].y + Xb[2].y,
                    Xa[3].x + Xb[3].x, Xa[3].y + Xb[3].y};
    *reinterpret_cast<v4f*>(&part[wave][row][e0])     = lo;
    *reinterpret_cast<v4f*>(&part[wave][row][e0 + 4]) = hi;
    __syncthreads();
    if (tid < E_DIM) {
        float s = 0.0f;
        #pragma unroll
        for (int w = 0; w < WAVES_PER_WG; ++w)
            #pragma unroll
            for (int r = 0; r < 4; ++r)
                s += part[w][r][tid];
        if (ATOMIC)
            atomicAdd(&outp[b * E_DIM + tid], s);
        else
            outp[blockIdx.x * E_DIM + tid] = s;   // disjoint partial row
    }
}

// Fused-add DPP over full wave (for the final reduce kernels).
__device__ __forceinline__ float wave_sum_tail(float s) {
    s = dpp_add<0xB1>(s);
    s = dpp_add<0x4E>(s);
    s = dpp_add<0x141>(s);
    s = dpp_add<0x140>(s);
    s = s + __int_as_float(__builtin_amdgcn_update_dpp(
        0, __float_as_int(s), 0x142, 0xA, 0xF, true));   // row_bcast15 -> rows 1,3
    s = s + __int_as_float(__builtin_amdgcn_update_dpp(
        0, __float_as_int(s), 0x143, 0xC, 0xF, true));   // row_bcast31 -> rows 2,3
    return s;                                            // total in lane 63
}

// Partials path: reduce 64 WG-partials per batch (w-loop split across 2 half-
// blocks of threads), then tiny matmul on wave 0.
__global__ __launch_bounds__(256) void qtc_final_p(
    const float* __restrict__ part,    // [NUM_WG, E]
    const float* __restrict__ W,       // [E, C]
    const float* __restrict__ bias,    // [C]
    float*       __restrict__ out)     // [B, C]
{
    __shared__ float red[2][E_DIM];
    __shared__ float pooled[E_DIM];
    const int b   = blockIdx.x;
    const int tid = threadIdx.x;
    const int e   = tid & 127;
    const int h   = tid >> 7;          // 0 or 1: which half of the w-range
    const float* base = part + (size_t)b * WG_PER_B * E_DIM + e;
    float s = 0.0f;
    #pragma unroll 8
    for (int w = h * 32; w < h * 32 + 32; ++w)
        s += base[w * E_DIM];
    red[h][e] = s;
    __syncthreads();
    if (tid < E_DIM)
        pooled[tid] = red[0][tid] + red[1][tid];
    __syncthreads();
    if (tid < 64) {
        const int lane = tid;
        const int e0 = 2 * lane;
        const float p0 = pooled[e0];
        const float p1 = pooled[e0 + 1];
        float acc[C_CLS];
        #pragma unroll
        for (int c = 0; c < C_CLS; ++c)
            acc[c] = fmaf(p0, W[e0 * C_CLS + c], p1 * W[(e0 + 1) * C_CLS + c]);
        #pragma unroll
        for (int c = 0; c < C_CLS; ++c)
            acc[c] = wave_sum_tail(acc[c]);
        if (lane == 63) {
            #pragma unroll
            for (int c = 0; c < C_CLS; ++c)
                out[b * C_CLS + c] = fmaf(acc[c], 1.0f / (float)T_LEN, bias[c]);
        }
    }
}

// Atomic-pooled fallback final (pooled[B,E] already summed).
__global__ __launch_bounds__(64) void qtc_final_a(
    const float* __restrict__ pooled,  // [B, E]
    const float* __restrict__ W,
    const float* __restrict__ bias,
    float*       __restrict__ out)
{
    const int b    = blockIdx.x;
    const int lane = threadIdx.x;
    const int e0   = 2 * lane;
    const float p0 = pooled[b * E_DIM + e0];
    const float p1 = pooled[b * E_DIM + e0 + 1];
    float acc[C_CLS];
    #pragma unroll
    for (int c = 0; c < C_CLS; ++c)
        acc[c] = fmaf(p0, W[e0 * C_CLS + c], p1 * W[(e0 + 1) * C_CLS + c]);
    #pragma unroll
    for (int c = 0; c < C_CLS; ++c)
        acc[c] = wave_sum_tail(acc[c]);
    if (lane == 63) {
        #pragma unroll
        for (int c = 0; c < C_CLS; ++c)
            out[b * C_CLS + c] = fmaf(acc[c], 1.0f / (float)T_LEN, bias[c]);
    }
}

extern "C" void kernel_launch(void* const* d_in, const int* in_sizes, int n_in,
                              void* d_out, int out_size, void* d_ws, size_t ws_size,
                              hipStream_t stream) {
    const int*   tokens = (const int*)  d_in[0];
    const float* emb    = (const float*)d_in[1];
    const float* g1     = (const float*)d_in[2];
    const float* b1     = (const float*)d_in[3];
    const float* g2     = (const float*)d_in[4];
    const float* b2     = (const float*)d_in[5];
    // d_in[6] = q_weights: provably unused by the reference
    const float* W      = (const float*)d_in[7];
    const float* bias   = (const float*)d_in[8];
    float* out = (float*)d_out;

    const size_t part_bytes = (size_t)NUM_WG * E_DIM * sizeof(float);  // 1 MB
    if (ws_size >= part_bytes) {
        float* part = (float*)d_ws;
        qtc_main<false><<<NUM_WG, 256, 0, stream>>>(tokens, emb, g1, b1, g2, b2, part);
        qtc_final_p<<<B_SZ, 256, 0, stream>>>(part, W, bias, out);
    } else {
        float* pooled = (float*)d_ws;  // 16 KB
        hipMemsetAsync(pooled, 0, B_SZ * E_DIM * sizeof(float), stream);
        qtc_main<true><<<NUM_WG, 256, 0, stream>>>(tokens, emb, g1, b1, g2, b2, pooled);
        qtc_final_a<<<B_SZ, 64, 0, stream>>>(pooled, W, bias, out);
    }
}